// Round 2
// baseline (375.996 us; speedup 1.0000x reference)
//
#include <hip/hip_runtime.h>
#include <climits>
#include <cstdint>

#define L 1000        // NUM_LABELS
#define NROWS 32768   // 64*512

// ws layout (int32 units):
//   [0,    1000)   first_row[label]  (INT_MAX if unseen)
//   [1024, 2048)   evt_g[rank] = (lab<<10)|m   -- compacted, rank-indexed
//   [2048, 3048)   perm_g[pos]

__global__ void k_init(int* __restrict__ first_row) {
    int i = blockIdx.x * blockDim.x + threadIdx.x;
    if (i < L) first_row[i] = INT_MAX;
}

__global__ void k_first(const int* __restrict__ labels, int* __restrict__ first_row) {
    int i = blockIdx.x * blockDim.x + threadIdx.x;
    if (i < NROWS) atomicMin(&first_row[labels[i]], i);
}

// One block per label: argmax of the first-occurrence row (first-index tiebreak)
// AND the event's rank = #{labels with smaller first_row} (first_row distinct,
// absent labels hold INT_MAX >= NROWS so they never count). Writes evt_g
// directly compacted in row order -- no 32K-slot scan needed downstream.
__global__ void k_argmax(const float* __restrict__ flat, const int* __restrict__ first_row,
                         int* __restrict__ evt_g) {
    int lab = blockIdx.x;
    int row = first_row[lab];
    if (row >= NROWS) return;                 // label absent (block-uniform)
    const float* y = flat + (size_t)row * L;
    int tid = threadIdx.x;
    float bv = -INFINITY;
    int bk = 0x7fffffff;
    for (int k = tid; k < L; k += 256) {
        float v = y[k];
        if (v > bv) { bv = v; bk = k; }       // ascending k => strict > keeps first
    }
    int cnt = 0;                              // rank partial (first_row is L2-hot)
    for (int j = tid; j < L; j += 256) cnt += (first_row[j] < row) ? 1 : 0;
    __shared__ float sv[256];
    __shared__ int   sk[256];
    __shared__ int   sc[256];
    sv[tid] = bv; sk[tid] = bk; sc[tid] = cnt;
    __syncthreads();
    for (int off = 128; off > 0; off >>= 1) {
        if (tid < off) {
            float v2 = sv[tid + off]; int k2 = sk[tid + off];
            if (v2 > sv[tid] || (v2 == sv[tid] && k2 < sk[tid])) { sv[tid] = v2; sk[tid] = k2; }
            sc[tid] += sc[tid + off];
        }
        __syncthreads();
    }
    if (tid == 0) evt_g[sc[0]] = (lab << 10) | sk[0];
}

// Single block. Replay the K transpositions serially on thread 0.
//
// Software pipeline (single wave; C++ program order preserves same-thread
// LDS read-after-write semantics):
//   - event words held 3 deep in registers (e2 = evt[i+2] value; evt[i+3]
//     read issued each iter) so event decode is never on the critical path.
//   - pos[] speculative reads 2 deep: (nPm,nPl) for iter i+2 are issued at
//     iter i BEFORE iter i's writes (so they see state i-1) and are patched
//     against the writes of iter i (patch-B) and iter i+1 (patch-A, next
//     iteration). Write addresses r/lab are distinct inside the swap branch
//     so each patch key matches at most one write.
//   - the only dependent-latency op left per iter is pos[r] (address is
//     data-dependent); it is issued first thing in the iteration.
// Critical path/iter: pos[r] (~120cy) + patch ALU ~= 150cy, vs ~290cy before
// (evt->addr->pos->consume chain was serialized at 1-deep prefetch).
__global__ void __launch_bounds__(1024) k_seq(const int* __restrict__ first_row,
                                              const int* __restrict__ evt_g,
                                              int* __restrict__ perm_g) {
    __shared__ int evt[1008];
    __shared__ int pos[L];
    int tid = threadIdx.x;
    int present = (tid < L) && (first_row[tid] < NROWS);
    int K = __syncthreads_count(present);     // #events == #present labels
    if (tid < K) evt[tid] = evt_g[tid];
    if (tid >= K && tid < K + 4) evt[tid] = 0;   // pad: harmless (m=lab=0), never consumed
    if (tid < L) pos[tid] = tid;              // pos = idx_sel^{-1}, initially identity
    __syncthreads();
    if (tid == 0 && K > 0) {
        int e0 = evt[0], e1 = evt[1], e2 = evt[2];
        int m   = e0 & 1023, lab = e0 >> 10;
        int Pm  = m,  Plab = lab;             // identity state: no reads needed
        int m1  = e1 & 1023, l1  = e1 >> 10;
        int Pm1 = m1, Pl1 = l1;               // identity (= state -1); patch-A at iter 0
        for (int i = 0; i < K; i++) {
            int r  = Pm;                      // fully patched -> final value
            int pr = pos[r];                  // the one dependent read: issue FIRST
            int m2 = e2 & 1023, l2 = e2 >> 10;
            int nPm = pos[m2];                // iter i+2 reads, state i-1
            int nPl = pos[l2];
            int e3  = evt[i + 3];
            if (r != lab) {
                pos[r]   = Plab;              // swap columns r <-> lab
                pos[lab] = pr;
                // patch-A: iter i+1 values (currently at state i-1) -> state i
                if      (m1 == r)   Pm1 = Plab;
                else if (m1 == lab) Pm1 = pr;
                if      (l1 == r)   Pl1 = Plab;
                else if (l1 == lab) Pl1 = pr;
                // patch-B: iter i+2 values (read this iter at state i-1) -> state i;
                // they get patch-A against iter i+1's writes next iteration.
                if      (m2 == r)   nPm = Plab;
                else if (m2 == lab) nPm = pr;
                if      (l2 == r)   nPl = Plab;
                else if (l2 == lab) nPl = pr;
            }
            m  = m1; lab = l1; Pm  = Pm1; Plab = Pl1;
            m1 = m2; l1  = l2; Pm1 = nPm; Pl1  = nPl;
            e2 = e3;
        }
    }
    __syncthreads();
    if (tid < L) perm_g[pos[tid]] = tid;      // invert: perm[pos[v]] = v
}

// 4 rows per block IN PARALLEL (four 256-thread groups sharing the p table).
// Global read and write fully coalesced float4; permuted gather goes via LDS.
__global__ void __launch_bounds__(1024) k_gather(const float* __restrict__ flat,
                                                 const int* __restrict__ perm_g,
                                                 float* __restrict__ out) {
    __shared__ __align__(16) int   p[1024];
    __shared__ __align__(16) float buf[4][L];
    int tid = threadIdx.x;
    if (tid < L) p[tid] = perm_g[tid];
    int g = tid >> 8;            // group 0..3 -> row within block
    int t = tid & 255;           // lane-in-group
    size_t row = (size_t)blockIdx.x * 4 + g;
    const float* src = flat + row * L;
    float*       dst = out  + row * L;
    float4 v;
    if (t < 250) v = ((const float4*)src)[t];
    __syncthreads();             // p visible; (v still in flight is fine)
    if (t < 250) ((float4*)buf[g])[t] = v;
    __syncthreads();             // buf visible
    if (t < 250) {
        int j = t * 4;
        float4 o;
        o.x = buf[g][p[j + 0]];
        o.y = buf[g][p[j + 1]];
        o.z = buf[g][p[j + 2]];
        o.w = buf[g][p[j + 3]];
        ((float4*)dst)[t] = o;
    }
}

extern "C" void kernel_launch(void* const* d_in, const int* in_sizes, int n_in,
                              void* d_out, int out_size, void* d_ws, size_t ws_size,
                              hipStream_t stream) {
    const float* flat   = (const float*)d_in[0];   // (64,512,1000) fp32
    const int*   labels = (const int*)d_in[1];     // (64,512) int32
    float* out = (float*)d_out;
    int* ws = (int*)d_ws;
    int* first_row = ws;          // 1000
    int* evt_g     = ws + 1024;   // 1000 (rank-compacted events)
    int* perm_g    = ws + 2048;   // 1000

    k_init  <<<(L + 255) / 256, 256, 0, stream>>>(first_row);
    k_first <<<(NROWS + 255) / 256, 256, 0, stream>>>(labels, first_row);
    k_argmax<<<L, 256, 0, stream>>>(flat, first_row, evt_g);
    k_seq   <<<1, 1024, 0, stream>>>(first_row, evt_g, perm_g);
    k_gather<<<NROWS / 4, 1024, 0, stream>>>(flat, perm_g, out);
}

// Round 3
// 307.641 us; speedup vs baseline: 1.2222x; 1.2222x over previous
//
#include <hip/hip_runtime.h>
#include <climits>
#include <cstdint>

#define L 1000        // NUM_LABELS
#define NROWS 32768   // 64*512

// ws layout (int32 units):
//   [0,    1000)   first_row[label]  (INT_MAX if unseen)
//   [1024, 2048)   evt_g[rank] = (lab<<10)|m   -- compacted, rank-indexed
//   [2048, 3048)   perm_g[pos]

__global__ void k_init(int* __restrict__ first_row) {
    int i = blockIdx.x * blockDim.x + threadIdx.x;
    if (i < L) first_row[i] = INT_MAX;
}

__global__ void k_first(const int* __restrict__ labels, int* __restrict__ first_row) {
    int i = blockIdx.x * blockDim.x + threadIdx.x;
    if (i < NROWS) atomicMin(&first_row[labels[i]], i);
}

// One block per label: argmax of the first-occurrence row (first-index tiebreak)
// AND the event's rank = #{labels with smaller first_row} (first_row distinct,
// absent labels hold INT_MAX so they never count). Writes evt_g directly
// compacted in row order -- no 32K-slot scan needed downstream.
__global__ void k_argmax(const float* __restrict__ flat, const int* __restrict__ first_row,
                         int* __restrict__ evt_g) {
    int lab = blockIdx.x;
    int row = first_row[lab];
    if (row >= NROWS) return;                 // label absent (block-uniform)
    const float* y = flat + (size_t)row * L;
    int tid = threadIdx.x;
    float bv = -INFINITY;
    int bk = 0x7fffffff;
    for (int k = tid; k < L; k += 256) {
        float v = y[k];
        if (v > bv) { bv = v; bk = k; }       // ascending k => strict > keeps first
    }
    int cnt = 0;                              // rank partial (first_row is L2-hot)
    for (int j = tid; j < L; j += 256) cnt += (first_row[j] < row) ? 1 : 0;
    __shared__ float sv[256];
    __shared__ int   sk[256];
    __shared__ int   sc[256];
    sv[tid] = bv; sk[tid] = bk; sc[tid] = cnt;
    __syncthreads();
    for (int off = 128; off > 0; off >>= 1) {
        if (tid < off) {
            float v2 = sv[tid + off]; int k2 = sk[tid + off];
            if (v2 > sv[tid] || (v2 == sv[tid] && k2 < sk[tid])) { sv[tid] = v2; sk[tid] = k2; }
            sc[tid] += sc[tid + off];
        }
        __syncthreads();
    }
    if (tid == 0) evt_g[sc[0]] = (lab << 10) | sk[0];
}

// Single block. Replay the K transpositions serially on thread 0.
//
// Half-iteration-rotated software pipeline (single wave; DS ops execute in
// issue order, so a read issued AFTER this iteration's writes sees state i):
//   - r_{i+1} is finalized INSIDE iter i (Pm1 patched vs iter i's two
//     writes), so the dependent read pos[r_{i+1}] is ISSUED at the bottom
//     of iter i, after the writes -> sees state i EXACTLY, zero patching.
//     Its ~120cy latency overlaps the loop back-edge + top-of-iter work.
//   - m/lab speculative reads for iter i+2 are likewise issued after iter
//     i's writes (state i) -> need exactly ONE patch level (vs iter i+1's
//     writes), applied off the critical path.
//   - branchless: when r==lab the two writes are no-ops (Plab==pr) and the
//     patches still produce correct values, so no divergent branch at all.
// Critical chain/iter: read arrival -> 2 cselect (r_next) -> issue next
// read  ~= 145cy, vs ~350cy in the round-2 version (read consumed in the
// same iteration it was issued => full latency exposed + patch ALU serial).
__global__ void __launch_bounds__(1024) k_seq(const int* __restrict__ first_row,
                                              const int* __restrict__ evt_g,
                                              int* __restrict__ perm_g) {
    __shared__ int evt[1008];
    __shared__ int pos[L];
    int tid = threadIdx.x;
    int present = (tid < L) && (first_row[tid] < NROWS);
    int K = __syncthreads_count(present);     // #events == #present labels
    if (tid < K) evt[tid] = evt_g[tid];
    if (tid >= K && tid < K + 4) evt[tid] = 0;   // pad (m=lab=0): reads harmless, never consumed
    if (tid < L) pos[tid] = tid;              // pos = idx_sel^{-1}, initially identity
    __syncthreads();
    if (tid == 0 && K > 0) {
        int e0 = evt[0], e1 = evt[1];
        int e2 = evt[2], e3 = evt[3];
        int r    = e0 & 1023, lab = e0 >> 10; // iter 0: r_0 = pos_{-1}[m_0] = m_0
        int Plab = lab;                       // pos_{-1}[lab_0] = lab_0 (identity)
        int pr   = r;                         // pos_{-1}[r_0]   = r_0   (identity)
        int m1 = e1 & 1023, l1 = e1 >> 10;
        int Pm1 = m1, Pl1 = l1;               // state -1 (identity); patched vs iter 0 writes
        for (int i = 0; i < K; i++) {
            pos[r]   = Plab;                  // iter i writes (no-ops when r==lab)
            pos[lab] = pr;
            // finalize iter i+1: patch state-(i-1) values vs iter i's writes
            int rn  = (m1 == r) ? Plab : (m1 == lab) ? pr : Pm1;  // r_{i+1} FINAL
            int prn = pos[rn];                // issued after writes -> state i, exact
            int Pln = (l1 == r) ? Plab : (l1 == lab) ? pr : Pl1;  // Plab_{i+1} FINAL
            // issue iter i+2 m/lab reads (state i; one patch level at iter i+1)
            int m2 = e2 & 1023, l2 = e2 >> 10;
            int Pm2 = pos[m2];
            int Pl2 = pos[l2];
            int e4  = evt[i + 4];
            // rotate
            r = rn; lab = l1; Plab = Pln; pr = prn;
            m1 = m2; l1 = l2; Pm1 = Pm2; Pl1 = Pl2;
            e2 = e3; e3 = e4;
        }
    }
    __syncthreads();
    if (tid < L) perm_g[pos[tid]] = tid;      // invert: perm[pos[v]] = v
}

// 4 rows per block IN PARALLEL (four 256-thread groups sharing the p table).
// Global read and write fully coalesced float4; permuted gather goes via LDS.
__global__ void __launch_bounds__(1024) k_gather(const float* __restrict__ flat,
                                                 const int* __restrict__ perm_g,
                                                 float* __restrict__ out) {
    __shared__ __align__(16) int   p[1024];
    __shared__ __align__(16) float buf[4][L];
    int tid = threadIdx.x;
    if (tid < L) p[tid] = perm_g[tid];
    int g = tid >> 8;            // group 0..3 -> row within block
    int t = tid & 255;           // lane-in-group
    size_t row = (size_t)blockIdx.x * 4 + g;
    const float* src = flat + row * L;
    float*       dst = out  + row * L;
    float4 v;
    if (t < 250) v = ((const float4*)src)[t];
    __syncthreads();             // p visible; (v still in flight is fine)
    if (t < 250) ((float4*)buf[g])[t] = v;
    __syncthreads();             // buf visible
    if (t < 250) {
        int j = t * 4;
        float4 o;
        o.x = buf[g][p[j + 0]];
        o.y = buf[g][p[j + 1]];
        o.z = buf[g][p[j + 2]];
        o.w = buf[g][p[j + 3]];
        ((float4*)dst)[t] = o;
    }
}

extern "C" void kernel_launch(void* const* d_in, const int* in_sizes, int n_in,
                              void* d_out, int out_size, void* d_ws, size_t ws_size,
                              hipStream_t stream) {
    const float* flat   = (const float*)d_in[0];   // (64,512,1000) fp32
    const int*   labels = (const int*)d_in[1];     // (64,512) int32
    float* out = (float*)d_out;
    int* ws = (int*)d_ws;
    int* first_row = ws;          // 1000
    int* evt_g     = ws + 1024;   // 1000 (rank-compacted events)
    int* perm_g    = ws + 2048;   // 1000

    k_init  <<<(L + 255) / 256, 256, 0, stream>>>(first_row);
    k_first <<<(NROWS + 255) / 256, 256, 0, stream>>>(labels, first_row);
    k_argmax<<<L, 256, 0, stream>>>(flat, first_row, evt_g);
    k_seq   <<<1, 1024, 0, stream>>>(first_row, evt_g, perm_g);
    k_gather<<<NROWS / 4, 1024, 0, stream>>>(flat, perm_g, out);
}